// Round 11
// baseline (141.819 us; speedup 1.0000x reference)
//
#include <hip/hip_runtime.h>

#define MD 4
#define DD 9          // 2*MD+1
#define KK 81         // DD*DD
#define B_ 4
#define C_ 128
#define H_ 192
#define W_ 192
#define HW (H_ * W_)
#define NWG 4608      // 2 chalf * 3 xt * 192 y * 4 b
#define PER_XCD (NWG / 8)

// out[b,c,y,x] = (1/C) * sum_{p,o} first[b,p*9+o,y,x] * second[b,c,y+p-4,x+o-4]
//
// Round 11: VMEM-instruction reduction sized to the allocator's revealed
// budget. Evidence r4 vs r10: +9 weight wave-loads/p cost +17us => the VMEM
// pipe is co-limiting (~7 cyc/wave-load); r8 (8-wide, 4ch) cut loads/FLOP
// but needed ~130 live regs vs the ~68 granted -> reload-per-use collapse.
// This round: 8-wide x-run x 2 CHANNELS per thread:
//   - per p: 8 window wave-loads (r4: 12, r10: 21); FMA:VMEM = 18:1.
//   - fo from LDS (2x ds_read_b128 per o, 8-way broadcast, 2-way bank=free);
//     edge weights zeroed at stage time (proven r5-r9, absmax unchanged).
//   - no unpack: FMA reads w[j+o] directly (static indices, rule #20 ok).
//   - live set ~70 VGPR = what the allocator gives naturally; windows feed
//     72 FMAs across the o-loop so loads structurally cannot sink.
// Block: 256 thr = 8 xr (8 px) x 32 cg (2 ch). Grid 4608 XCD-swizzled.
// Sentinels: WRITE_SIZE == 73728 KB exactly; VALUBusy(prof) >= 40% else
// register collapse -> revert to round-4 exact.

__global__ __launch_bounds__(256)
void corr_transpose_kernel(const float* __restrict__ first,
                           const float* __restrict__ second,
                           float* __restrict__ out) {
  __shared__ __align__(16) float ldsF[KK * 64];

  // bijective XCD swizzle (4608 % 8 == 0), y-fastest within an XCD chunk
  const int lin = blockIdx.x;
  const int wid = (lin & 7) * PER_XCD + (lin >> 3);
  const int y     = wid % H_;
  const int t     = wid / H_;          // 0..23
  const int chalf = t & 1;
  const int xt0   = ((t >> 1) % 3) * 64;
  const int b     = t / 6;

  const int tid = threadIdx.x;

  // ---- stage first[b,:,y,xt0..+63] into LDS with X-edge weight masking ----
  {
    const float* fbase = first + ((size_t)(b * KK) * H_ + y) * (size_t)W_ + xt0;
    const bool edge = (xt0 != 64);     // block-uniform
    for (int idx = tid; idx < KK * 16; idx += 256) {
      const int k  = idx >> 4;
      const int xi = (idx & 15) << 2;
      float4 v = *reinterpret_cast<const float4*>(fbase + (size_t)k * HW + xi);
      if (edge) {
        const int o    = k % DD;
        const int base = xt0 + xi + o - MD;   // second-x for component 0
        if (base + 0 < 0 || base + 0 >= W_) v.x = 0.f;
        if (base + 1 < 0 || base + 1 >= W_) v.y = 0.f;
        if (base + 2 < 0 || base + 2 >= W_) v.z = 0.f;
        if (base + 3 < 0 || base + 3 >= W_) v.w = 0.f;
      }
      *reinterpret_cast<float4*>(&ldsF[k * 64 + xi]) = v;
    }
  }

  const int xr = tid & 7;            // 8 x-runs of 8 pixels
  const int cg = tid >> 3;           // 0..31, 2 channels each
  const int x0 = xt0 + xr * 8;
  const int c0 = chalf * 64 + cg * 2;

  // window float4 start offsets (floats), clamped in-bounds.
  // OOB float4s are whole (multiples of 4) and their weights are zeroed.
  int off0 = x0 - 4, off1 = x0, off2 = x0 + 4, off3 = x0 + 8;
  if (off0 < 0) off0 = 0;                  // xt0==0, xr==0
  if (off3 > W_ - 4) off3 = W_ - 4;        // xt0==128, xr==7

  // p-loop bounds hoisted (block-uniform)
  const int pstart = (y >= MD) ? 0 : (MD - y);
  const int pend   = (y + MD < H_) ? DD : (H_ + MD - y);
  const int yy0    = y + pstart - MD;

  const float* secB = second + (size_t)b * C_ * HW;
  const float* rp0 = secB + ((size_t)c0 * H_ + yy0) * (size_t)W_;
  const float* rp1 = rp0 + HW;

  __syncthreads();

  float acc0[8], acc1[8];
#pragma unroll
  for (int j = 0; j < 8; ++j) { acc0[j] = 0.f; acc1[j] = 0.f; }

  for (int p = pstart; p < pend; ++p) {
    // 16-float windows: second[c, yy, x0-4 .. x0+11], 4 aligned float4 each
    float w0[16], w1[16];
    *reinterpret_cast<float4*>(&w0[0])  = *reinterpret_cast<const float4*>(rp0 + off0);
    *reinterpret_cast<float4*>(&w0[4])  = *reinterpret_cast<const float4*>(rp0 + off1);
    *reinterpret_cast<float4*>(&w0[8])  = *reinterpret_cast<const float4*>(rp0 + off2);
    *reinterpret_cast<float4*>(&w0[12]) = *reinterpret_cast<const float4*>(rp0 + off3);
    *reinterpret_cast<float4*>(&w1[0])  = *reinterpret_cast<const float4*>(rp1 + off0);
    *reinterpret_cast<float4*>(&w1[4])  = *reinterpret_cast<const float4*>(rp1 + off1);
    *reinterpret_cast<float4*>(&w1[8])  = *reinterpret_cast<const float4*>(rp1 + off2);
    *reinterpret_cast<float4*>(&w1[12]) = *reinterpret_cast<const float4*>(rp1 + off3);

#pragma unroll
    for (int o = 0; o < DD; ++o) {
      // first[p*9+o, y, x0..x0+7]: 8-way broadcast across cg, 2-way banks
      float fo8[8];
      *reinterpret_cast<float4*>(&fo8[0]) =
          *reinterpret_cast<const float4*>(&ldsF[(p * DD + o) * 64 + xr * 8]);
      *reinterpret_cast<float4*>(&fo8[4]) =
          *reinterpret_cast<const float4*>(&ldsF[(p * DD + o) * 64 + xr * 8 + 4]);
#pragma unroll
      for (int j = 0; j < 8; ++j) {
        acc0[j] = fmaf(fo8[j], w0[j + o], acc0[j]);
        acc1[j] = fmaf(fo8[j], w1[j + o], acc1[j]);
      }
    }

    rp0 += W_; rp1 += W_;
  }

  const float inv_c = 1.0f / (float)C_;
  float* outB = out + (size_t)b * C_ * HW + (size_t)y * W_ + x0;
  {
    float4 v;
    v.x = acc0[0] * inv_c; v.y = acc0[1] * inv_c;
    v.z = acc0[2] * inv_c; v.w = acc0[3] * inv_c;
    *reinterpret_cast<float4*>(outB + (size_t)(c0 + 0) * HW) = v;
    v.x = acc0[4] * inv_c; v.y = acc0[5] * inv_c;
    v.z = acc0[6] * inv_c; v.w = acc0[7] * inv_c;
    *reinterpret_cast<float4*>(outB + (size_t)(c0 + 0) * HW + 4) = v;
    v.x = acc1[0] * inv_c; v.y = acc1[1] * inv_c;
    v.z = acc1[2] * inv_c; v.w = acc1[3] * inv_c;
    *reinterpret_cast<float4*>(outB + (size_t)(c0 + 1) * HW) = v;
    v.x = acc1[4] * inv_c; v.y = acc1[5] * inv_c;
    v.z = acc1[6] * inv_c; v.w = acc1[7] * inv_c;
    *reinterpret_cast<float4*>(outB + (size_t)(c0 + 1) * HW + 4) = v;
  }
}

extern "C" void kernel_launch(void* const* d_in, const int* in_sizes, int n_in,
                              void* d_out, int out_size, void* d_ws, size_t ws_size,
                              hipStream_t stream) {
  const float* first  = (const float*)d_in[0];
  const float* second = (const float*)d_in[1];
  float* out = (float*)d_out;

  corr_transpose_kernel<<<dim3(NWG), 256, 0, stream>>>(first, second, out);
}

// Round 12
// 85.178 us; speedup vs baseline: 1.6650x; 1.6650x over previous
//
#include <hip/hip_runtime.h>

#define MD 4
#define DD 9          // 2*MD+1
#define KK 81         // DD*DD
#define B_ 4
#define C_ 128
#define H_ 192
#define W_ 192
#define HW (H_ * W_)
#define NWG 2304      // 96 y-pairs * 3 xt * 2 chh * 4 b
#define PER_XCD (NWG / 8)

// out[b,c,y,x] = (1/C) * sum_{p,o} first[b,p*9+o,y,x] * second[b,c,y+p-4,x+o-4]
//
// Round 12: 2-row y-blocking sized UNDER the (256,2) pinned budget.
// Facts from r1-r11: launch_bounds(256,2) reliably PINS VGPR=128 (r2); any
// un-pinned structure collapses to ~48-72 regs and serializes (r5-r11).
// r2's only failure was needing ~140 regs -> 12-reg spill. So: build a
// structure needing ~100:
//   thread = 4x * 4ch * 2y (acc 32). Each second-row window (12 floats/ch)
//   feeds BOTH output rows: p=r for y0, p=r-1 for y0+1 -> 12 window loads
//   serve 288 FMAs per row-iter (24:1 vs r4's 12:1). L1-side bytes halve
//   (~1.13GB, ~28us); ds_read:FMA stays 16:1 (~32us); FMA issue ~19.4us.
// LDS: TWO weight slabs (y0,y0+1), 41.5KB, stage-masked x-edges (proven).
// Live set: win 48 + acc 32 + fo 4 + ptrs ~12 ~= 100 < 128 -> no spill.
// Sentinels: VGPR_Count==128, WRITE_SIZE==73728KB exactly (else spill),
// absmax unchanged (same accumulation order as reference).

#define FMA16(A0, A1, A2, A3, FO, O)                                   \
  A0[0] = fmaf(FO.x, w0[(O) + 0], A0[0]);                              \
  A0[1] = fmaf(FO.y, w0[(O) + 1], A0[1]);                              \
  A0[2] = fmaf(FO.z, w0[(O) + 2], A0[2]);                              \
  A0[3] = fmaf(FO.w, w0[(O) + 3], A0[3]);                              \
  A1[0] = fmaf(FO.x, w1[(O) + 0], A1[0]);                              \
  A1[1] = fmaf(FO.y, w1[(O) + 1], A1[1]);                              \
  A1[2] = fmaf(FO.z, w1[(O) + 2], A1[2]);                              \
  A1[3] = fmaf(FO.w, w1[(O) + 3], A1[3]);                              \
  A2[0] = fmaf(FO.x, w2[(O) + 0], A2[0]);                              \
  A2[1] = fmaf(FO.y, w2[(O) + 1], A2[1]);                              \
  A2[2] = fmaf(FO.z, w2[(O) + 2], A2[2]);                              \
  A2[3] = fmaf(FO.w, w2[(O) + 3], A2[3]);                              \
  A3[0] = fmaf(FO.x, w3[(O) + 0], A3[0]);                              \
  A3[1] = fmaf(FO.y, w3[(O) + 1], A3[1]);                              \
  A3[2] = fmaf(FO.z, w3[(O) + 2], A3[2]);                              \
  A3[3] = fmaf(FO.w, w3[(O) + 3], A3[3]);

__global__ __launch_bounds__(256, 2)
void corr_transpose_kernel(const float* __restrict__ first,
                           const float* __restrict__ second,
                           float* __restrict__ out) {
  __shared__ __align__(16) float ldsF[2][KK * 64];

  // bijective XCD swizzle (2304 % 8 == 0), y-pair-fastest within an XCD chunk
  const int lin = blockIdx.x;
  const int wid = (lin & 7) * PER_XCD + (lin >> 3);
  const int yp  = wid % 96;
  const int t   = wid / 96;          // 0..23
  const int chh = t & 1;
  const int xt0 = ((t >> 1) % 3) * 64;
  const int b   = t / 6;
  const int y0  = yp * 2;            // output rows y0, y0+1

  const int tid = threadIdx.x;

  // ---- stage first[b,:,y0+slab,xt0..+63] into 2 LDS slabs, edge-masked ----
  const bool edge = (xt0 != 64);     // block-uniform
#pragma unroll
  for (int slab = 0; slab < 2; ++slab) {
    const float* fbase =
        first + ((size_t)(b * KK) * H_ + (y0 + slab)) * (size_t)W_ + xt0;
    for (int idx = tid; idx < KK * 16; idx += 256) {
      const int k  = idx >> 4;
      const int xi = (idx & 15) << 2;
      float4 v = *reinterpret_cast<const float4*>(fbase + (size_t)k * HW + xi);
      if (edge) {
        const int o    = k % DD;
        const int base = xt0 + xi + o - MD;   // second-x for component 0
        if (base + 0 < 0 || base + 0 >= W_) v.x = 0.f;
        if (base + 1 < 0 || base + 1 >= W_) v.y = 0.f;
        if (base + 2 < 0 || base + 2 >= W_) v.z = 0.f;
        if (base + 3 < 0 || base + 3 >= W_) v.w = 0.f;
      }
      *reinterpret_cast<float4*>(&ldsF[slab][k * 64 + xi]) = v;
    }
  }

  const int xg = tid & 15;
  const int cg = tid >> 4;
  const int c0 = chh * 64 + cg * 4;
  const int x0 = xt0 + xg * 4;

  // clamped window offsets; OOB float4s have zeroed weights in LDS
  const bool mA = (x0 != 0);
  const bool mE = (x0 + 8 <= W_);
  const int  oa = mA ? x0 - 4 : 0;
  const int  oe = mE ? x0 + 4 : W_ - 8;

  // row range: yy = y0-4+r, r in [r_lo, r_hi], yy clamped to [0,191]
  const int r_lo = (y0 >= MD) ? 0 : (MD - y0);
  const int r_hi = (195 - y0 < 9) ? (195 - y0) : 9;

  const float* secB = second + (size_t)b * C_ * HW;
  const float* rp0 =
      secB + ((size_t)(c0 + 0) * H_ + (y0 - MD + r_lo)) * (size_t)W_;
  const float* rp1 = rp0 + HW;
  const float* rp2 = rp1 + HW;
  const float* rp3 = rp2 + HW;

  __syncthreads();

  float a00[4] = {0.f, 0.f, 0.f, 0.f};   // dy0, ci=0..3
  float a01[4] = {0.f, 0.f, 0.f, 0.f};
  float a02[4] = {0.f, 0.f, 0.f, 0.f};
  float a03[4] = {0.f, 0.f, 0.f, 0.f};
  float a10[4] = {0.f, 0.f, 0.f, 0.f};   // dy1
  float a11[4] = {0.f, 0.f, 0.f, 0.f};
  float a12[4] = {0.f, 0.f, 0.f, 0.f};
  float a13[4] = {0.f, 0.f, 0.f, 0.f};

  for (int r = r_lo; r <= r_hi; ++r) {
    // windows: second[c0+ci, yy, x0-4 .. x0+7] (12 floats each)
    float w0[12], w1[12], w2[12], w3[12];
    *reinterpret_cast<float4*>(&w0[0]) = *reinterpret_cast<const float4*>(rp0 + oa);
    *reinterpret_cast<float4*>(&w0[4]) = *reinterpret_cast<const float4*>(rp0 + x0);
    *reinterpret_cast<float4*>(&w0[8]) = *reinterpret_cast<const float4*>(rp0 + oe);
    *reinterpret_cast<float4*>(&w1[0]) = *reinterpret_cast<const float4*>(rp1 + oa);
    *reinterpret_cast<float4*>(&w1[4]) = *reinterpret_cast<const float4*>(rp1 + x0);
    *reinterpret_cast<float4*>(&w1[8]) = *reinterpret_cast<const float4*>(rp1 + oe);
    *reinterpret_cast<float4*>(&w2[0]) = *reinterpret_cast<const float4*>(rp2 + oa);
    *reinterpret_cast<float4*>(&w2[4]) = *reinterpret_cast<const float4*>(rp2 + x0);
    *reinterpret_cast<float4*>(&w2[8]) = *reinterpret_cast<const float4*>(rp2 + oe);
    *reinterpret_cast<float4*>(&w3[0]) = *reinterpret_cast<const float4*>(rp3 + oa);
    *reinterpret_cast<float4*>(&w3[4]) = *reinterpret_cast<const float4*>(rp3 + x0);
    *reinterpret_cast<float4*>(&w3[8]) = *reinterpret_cast<const float4*>(rp3 + oe);

    if (r <= 8) {                       // dy=0 contribution, p = r
      const float* fbp = &ldsF[0][(r * DD) * 64 + (xg << 2)];
#pragma unroll
      for (int o = 0; o < DD; ++o) {
        const float4 fo = *reinterpret_cast<const float4*>(fbp + o * 64);
        FMA16(a00, a01, a02, a03, fo, o)
      }
    }
    if (r >= 1) {                       // dy=1 contribution, p = r-1
      const float* fbp = &ldsF[1][((r - 1) * DD) * 64 + (xg << 2)];
#pragma unroll
      for (int o = 0; o < DD; ++o) {
        const float4 fo = *reinterpret_cast<const float4*>(fbp + o * 64);
        FMA16(a10, a11, a12, a13, fo, o)
      }
    }

    rp0 += W_; rp1 += W_; rp2 += W_; rp3 += W_;
  }

  const float inv_c = 1.0f / (float)C_;
  float* ob0 = out + (size_t)b * C_ * HW + (size_t)y0 * W_ + x0;
  float* ob1 = ob0 + W_;
#define STORE4(PTR, CI, ACC)                                              \
  {                                                                       \
    float4 v;                                                             \
    v.x = ACC[0] * inv_c; v.y = ACC[1] * inv_c;                           \
    v.z = ACC[2] * inv_c; v.w = ACC[3] * inv_c;                           \
    *reinterpret_cast<float4*>(PTR + (size_t)(c0 + CI) * HW) = v;         \
  }
  STORE4(ob0, 0, a00)
  STORE4(ob0, 1, a01)
  STORE4(ob0, 2, a02)
  STORE4(ob0, 3, a03)
  STORE4(ob1, 0, a10)
  STORE4(ob1, 1, a11)
  STORE4(ob1, 2, a12)
  STORE4(ob1, 3, a13)
#undef STORE4
}

extern "C" void kernel_launch(void* const* d_in, const int* in_sizes, int n_in,
                              void* d_out, int out_size, void* d_ws, size_t ws_size,
                              hipStream_t stream) {
  const float* first  = (const float*)d_in[0];
  const float* second = (const float*)d_in[1];
  float* out = (float*)d_out;

  corr_transpose_kernel<<<dim3(NWG), 256, 0, stream>>>(first, second, out);
}